// Round 6
// baseline (310.348 us; speedup 1.0000x reference)
//
#include <hip/hip_runtime.h>
#include <hip/hip_bf16.h>
#include <math.h>

// SelectiveStateSpaceMixer — round 6: 256-tile 8-wave phased GEMM (T3/T4/T5)
// for gemm_in/gemm_out; dtbc single-pass BN=192; wave-shuffle scan.
// ws layout (bytes):
//   xzb    bf16[8192][4096]  67108864 @ 0
//   xb     bf16[8192][1024]  16777216 @ 67108864
//   xact   bf16[8192][2048]  33554432 @ 83886080
//   hb     bf16[8192][2048]  33554432 @ 117440512
//   dtbcT  f32 [192][8192]    6291456 @ 150994944
//   ybuf   f32 [8192][64]     2097152 @ 157286400
//   ynb    bf16[8192][64]     1048576 @ 159383552
//   WinT   bf16[4096][1024]   8388608 @ 160432128
//   WoutT  bf16[1024][2048]   4194304 @ 168820736
//   WdtbcT bf16[192][2048]     786432 @ 173015040
//   WsiT   bf16[2048][64]      262144 @ 173801472   end 174063616

namespace {

typedef __bf16 bf16x8 __attribute__((ext_vector_type(8)));
typedef float  f32x4  __attribute__((ext_vector_type(4)));
typedef unsigned short u16;

constexpr int kSeq = 4096;

__device__ __forceinline__ float sigmoid_f(float x) { return 1.0f / (1.0f + expf(-x)); }
__device__ __forceinline__ u16   f2bf(float f) { __bf16 h = (__bf16)f; return __builtin_bit_cast(u16, h); }
__device__ __forceinline__ float bf2f(u16 u)   { return (float)__builtin_bit_cast(__bf16, u); }

// async global->LDS, 16B per lane (dest = wave-uniform base + lane*16)
__device__ __forceinline__ void gll16(const u16* g, u16* l) {
    __builtin_amdgcn_global_load_lds(
        (const __attribute__((address_space(1))) unsigned int*)g,
        (__attribute__((address_space(3))) unsigned int*)l,
        16, 0, 0);
}

// bijective XCD-aware block swizzle (m204)
__device__ __forceinline__ int xcd_swizzle(int lin, int nwg) {
    const int q = nwg >> 3, r = nwg & 7;
    const int xcd = lin & 7, idx = lin >> 3;
    return (xcd < r ? xcd * (q + 1) : r * (q + 1) + (xcd - r) * q) + idx;
}

// ---------- fp32 -> bf16 elementwise ----------
__global__ __launch_bounds__(256)
void convert_bf16(const float* __restrict__ in, u16* __restrict__ out, long n4)
{
    long i = (long)blockIdx.x * 256 + threadIdx.x;
    if (i >= n4) return;
    float4 v = reinterpret_cast<const float4*>(in)[i];
    ushort4 o = make_ushort4(f2bf(v.x), f2bf(v.y), f2bf(v.z), f2bf(v.w));
    reinterpret_cast<ushort4*>(out)[i] = o;
}

// ---------- 32x32 tile transpose body: fp32 [R][C] -> bf16 [C][R] ----------
__device__ __forceinline__ void tr_body(float (*tile)[33],
                                        const float* __restrict__ in, u16* __restrict__ out,
                                        int R, int C, int r0, int c0, int t)
{
    const int lr = t >> 3, lc = (t & 7) * 4;
    float4 v = *reinterpret_cast<const float4*>(in + (size_t)(r0 + lr) * C + c0 + lc);
    tile[lr][lc + 0] = v.x; tile[lr][lc + 1] = v.y;
    tile[lr][lc + 2] = v.z; tile[lr][lc + 3] = v.w;
    __syncthreads();
    const int oc = t >> 3, orr = (t & 7) * 4;
    ushort4 o = make_ushort4(f2bf(tile[orr + 0][oc]), f2bf(tile[orr + 1][oc]),
                             f2bf(tile[orr + 2][oc]), f2bf(tile[orr + 3][oc]));
    *reinterpret_cast<ushort4*>(out + (size_t)(c0 + oc) * R + r0 + orr) = o;
}

__global__ __launch_bounds__(256)
void transpose_big(const float* __restrict__ Win, u16* __restrict__ WinT,
                   const float* __restrict__ Wout, u16* __restrict__ WoutT)
{
    __shared__ float tile[32][33];
    const int t = threadIdx.x;
    if (blockIdx.z == 0) {
        tr_body(tile, Win, WinT, 1024, 4096, blockIdx.y * 32, blockIdx.x * 32, t);
    } else {
        if (blockIdx.x >= 64) return;
        tr_body(tile, Wout, WoutT, 2048, 1024, blockIdx.x * 32, blockIdx.y * 32, t);
    }
}

__global__ __launch_bounds__(256)
void transpose_small(const float* __restrict__ Wdt, const float* __restrict__ WB,
                     const float* __restrict__ WC,  const float* __restrict__ Wsi,
                     u16* __restrict__ WdtbcT, u16* __restrict__ WsiT)
{
    __shared__ float tile[32][33];
    const int t = threadIdx.x;
    const int z = blockIdx.z;
    if (z < 3) {
        const float* in = (z == 0) ? Wdt : (z == 1) ? WB : WC;
        u16* out = WdtbcT + (size_t)z * 64 * 2048;
        tr_body(tile, in, out, 2048, 64, blockIdx.y * 32, blockIdx.x * 32, t);
    } else {
        tr_body(tile, Wsi, WsiT, 64, 2048, blockIdx.x * 32, blockIdx.y * 32, t);
    }
}

// ================= 256-tile 8-wave phased GEMM =================
// C[M][N] = A[M][K] @ Bt[N][K]^T + bias. 512 threads, wave grid WMxWN,
// BK=64 double-buffered LDS with the proven 8-row XOR swizzle (0 conflicts),
// 4 phases per K-tile: {2-ish gll16 prefetch | ds_read quadrant | barrier |
// setprio+MFMA+setprio | barrier}; one __syncthreads (vmcnt drain) per tile.
// EPI 0: fp32 out; EPI 1: bf16 out.
#define PHASE(PH, MH, NH, RDA, RDB)                                           \
  {                                                                           \
    if (t + 1 < nt) {                                                         \
      _Pragma("unroll")                                                       \
      for (int i = 0; i < NCA + NCB; ++i) {                                   \
        if ((i * 4) / (NCA + NCB) == (PH)) {                                  \
          if (i < NCA) {                                                      \
            const int ca = wid * NCA + i;                                     \
            gll16(A + (size_t)(row0 + ca * 8 + srow) * K + knext + scol,      \
                  abase_n + ca * 512 + lane * 8);                             \
          } else {                                                            \
            const int cb = wid * NCB + (i - NCA);                             \
            gll16(Bt + (size_t)(col0 + cb * 8 + srow) * K + knext + scol,     \
                  bbase_n + cb * 512 + lane * 8);                             \
          }                                                                   \
        }                                                                     \
      }                                                                       \
    }                                                                         \
    if (RDA) {                                                                \
      _Pragma("unroll")                                                       \
      for (int m = 0; m < FMH; ++m) {                                         \
        const int rr = wr + ((MH) * FMH + m) * 16 + fr;                       \
        _Pragma("unroll")                                                     \
        for (int kk = 0; kk < 2; ++kk)                                        \
          af[m][kk] = *reinterpret_cast<const bf16x8*>(                       \
              abase_c + rr * 64 + (((kk * 4 + fq) ^ (rr & 7)) * 8));          \
      }                                                                       \
    }                                                                         \
    if (RDB) {                                                                \
      _Pragma("unroll")                                                       \
      for (int n = 0; n < FNH; ++n) {                                         \
        const int rr = wc + ((NH) * FNH + n) * 16 + fr;                       \
        _Pragma("unroll")                                                     \
        for (int kk = 0; kk < 2; ++kk)                                        \
          bg[n][kk] = *reinterpret_cast<const bf16x8*>(                       \
              bbase_c + rr * 64 + (((kk * 4 + fq) ^ (rr & 7)) * 8));          \
      }                                                                       \
    }                                                                         \
    __builtin_amdgcn_s_barrier();                                             \
    __builtin_amdgcn_s_setprio(1);                                            \
    _Pragma("unroll")                                                         \
    for (int m = 0; m < FMH; ++m)                                             \
      _Pragma("unroll")                                                       \
      for (int n = 0; n < FNH; ++n)                                           \
        _Pragma("unroll")                                                     \
        for (int kk = 0; kk < 2; ++kk)                                        \
          acc[(MH) * FMH + m][(NH) * FNH + n] =                               \
              __builtin_amdgcn_mfma_f32_16x16x32_bf16(                        \
                  af[m][kk], bg[n][kk], acc[(MH) * FMH + m][(NH) * FNH + n],  \
                  0, 0, 0);                                                   \
    __builtin_amdgcn_s_setprio(0);                                            \
    __builtin_amdgcn_s_barrier();                                             \
  }

template <int BM, int BN, int WM, int WN, int EPI>
__global__ __launch_bounds__(512, 2)
void gemm256(const u16* __restrict__ A, const u16* __restrict__ Bt,
             const float* __restrict__ b0, void* __restrict__ o0,
             int N, int K, int nbx)
{
    constexpr int WTM = BM / WM, WTN = BN / WN;      // wave tile
    constexpr int FM  = WTM / 16, FN = WTN / 16;     // fragments per wave
    constexpr int FMH = FM / 2,  FNH = FN / 2;       // per-quadrant fragments
    constexpr int NCA = BM / 64, NCB = BN / 64;      // 1KB stage chunks per wave

    __shared__ __align__(16) u16 As[2][BM * 64];
    __shared__ __align__(16) u16 Bs[2][BN * 64];

    const int tid  = threadIdx.x;
    const int lane = tid & 63;
    const int wid  = tid >> 6;
    const int wr   = (wid / WN) * WTM;
    const int wc   = (wid % WN) * WTN;
    const int swz  = xcd_swizzle(blockIdx.x, gridDim.x);
    const int row0 = (swz / nbx) * BM;
    const int col0 = (swz % nbx) * BN;

    const int srow = lane >> 3;                      // row within 8-row chunk
    const int scol = ((lane & 7) ^ srow) * 8;        // pre-swizzled global col
    const int fr   = lane & 15;
    const int fq   = lane >> 4;

    const int nt = K / 64;

    f32x4 acc[FM][FN];
#pragma unroll
    for (int m = 0; m < FM; ++m)
#pragma unroll
        for (int n = 0; n < FN; ++n) acc[m][n] = (f32x4){0.f, 0.f, 0.f, 0.f};

    // prologue: stage tile 0 into buffer 0
#pragma unroll
    for (int i = 0; i < NCA + NCB; ++i) {
        if (i < NCA) {
            const int ca = wid * NCA + i;
            gll16(A + (size_t)(row0 + ca * 8 + srow) * K + scol,
                  &As[0][0] + ca * 512 + lane * 8);
        } else {
            const int cb = wid * NCB + (i - NCA);
            gll16(Bt + (size_t)(col0 + cb * 8 + srow) * K + scol,
                  &Bs[0][0] + cb * 512 + lane * 8);
        }
    }
    __syncthreads();

    bf16x8 af[FMH][2], bg[FNH][2];

    for (int t = 0; t < nt; ++t) {
        const int cur = t & 1;
        u16* abase_c = &As[cur][0];
        u16* bbase_c = &Bs[cur][0];
        u16* abase_n = &As[cur ^ 1][0];
        u16* bbase_n = &Bs[cur ^ 1][0];
        const int knext = (t + 1) * 64;

        PHASE(0, 0, 0, true,  true)
        PHASE(1, 0, 1, false, true)
        PHASE(2, 1, 1, true,  false)
        PHASE(3, 1, 0, false, true)

        __syncthreads();   // drains vmcnt: tile t+1 staged, all reads of cur done
    }

    // epilogue
#pragma unroll
    for (int m = 0; m < FM; ++m) {
#pragma unroll
        for (int n = 0; n < FN; ++n) {
            const int gc  = col0 + wc + n * 16 + fr;
            const int gr0 = row0 + wr + m * 16 + fq * 4;
#pragma unroll
            for (int j = 0; j < 4; ++j) {
                const float v = acc[m][n][j] + b0[gc];
                if constexpr (EPI == 0) {
                    ((float*)o0)[(size_t)(gr0 + j) * N + gc] = v;
                } else {
                    ((u16*)o0)[(size_t)(gr0 + j) * N + gc] = f2bf(v);
                }
            }
        }
    }
}
#undef PHASE

// ---------- 4-wave 2-barrier MFMA GEMM (dtbc / mix epilogues) ----------
// EPI 2: fp32 TRANSPOSED out [N][8192]; bias b0|b1|b2 per 64-col; sigmoid col<64
// EPI 3: mix: bf16 out = (acc + b_si + D*xact) * sigmoid(gate)
template <int BM, int BN, int EPI>
__global__ __launch_bounds__(256)
void gemm_mfma(const u16* __restrict__ A, const u16* __restrict__ Bt,
               const float* __restrict__ b0, const float* __restrict__ b1,
               const float* __restrict__ b2,
               const u16* __restrict__ aux0, const u16* __restrict__ aux1,
               void* __restrict__ o0, int N, int K, int nbx)
{
    constexpr int FM = BM / 32, FN = BN / 32;
    constexpr int CA = BM / 32, CB = BN / 32;
    __shared__ __align__(16) u16 As[BM][64];
    __shared__ __align__(16) u16 Bs[BN][64];

    const int tid  = threadIdx.x;
    const int lane = tid & 63;
    const int wid  = tid >> 6;
    const int wr   = (wid >> 1) * (BM / 2);
    const int wc   = (wid & 1)  * (BN / 2);
    const int swz  = xcd_swizzle(blockIdx.x, gridDim.x);
    const int row0 = (swz / nbx) * BM;
    const int col0 = (swz % nbx) * BN;

    const int srow = lane >> 3;
    const int scol = ((lane & 7) ^ srow) * 8;
    const int fr   = lane & 15;
    const int fq   = lane >> 4;

    f32x4 acc[FM][FN];
#pragma unroll
    for (int m = 0; m < FM; ++m)
#pragma unroll
        for (int n = 0; n < FN; ++n) acc[m][n] = (f32x4){0.f, 0.f, 0.f, 0.f};

    for (int k0 = 0; k0 < K; k0 += 64) {
#pragma unroll
        for (int i = 0; i < CA; ++i) {
            const int c = wid * CA + i;
            gll16(A + (size_t)(row0 + c * 8 + srow) * K + k0 + scol,
                  &As[0][0] + c * 512 + lane * 8);
        }
#pragma unroll
        for (int i = 0; i < CB; ++i) {
            const int c = wid * CB + i;
            gll16(Bt + (size_t)(col0 + c * 8 + srow) * K + k0 + scol,
                  &Bs[0][0] + c * 512 + lane * 8);
        }
        __syncthreads();
#pragma unroll
        for (int kk = 0; kk < 2; ++kk) {
            bf16x8 af[FM], bg[FN];
#pragma unroll
            for (int m = 0; m < FM; ++m) {
                const int rr = wr + m * 16 + fr;
                af[m] = *reinterpret_cast<const bf16x8*>(
                    &As[rr][(kk * 32 + fq * 8) ^ ((rr & 7) * 8)]);
            }
#pragma unroll
            for (int n = 0; n < FN; ++n) {
                const int rr = wc + n * 16 + fr;
                bg[n] = *reinterpret_cast<const bf16x8*>(
                    &Bs[rr][(kk * 32 + fq * 8) ^ ((rr & 7) * 8)]);
            }
#pragma unroll
            for (int m = 0; m < FM; ++m)
#pragma unroll
                for (int n = 0; n < FN; ++n)
                    acc[m][n] = __builtin_amdgcn_mfma_f32_16x16x32_bf16(af[m], bg[n], acc[m][n], 0, 0, 0);
        }
        __syncthreads();
    }

#pragma unroll
    for (int m = 0; m < FM; ++m) {
#pragma unroll
        for (int n = 0; n < FN; ++n) {
            const int gc  = col0 + wc + n * 16 + fr;
            const int gr0 = row0 + wr + m * 16 + fq * 4;
            if constexpr (EPI == 2) {
                float4 vv;
                float* vp = (float*)&vv;
#pragma unroll
                for (int j = 0; j < 4; ++j) {
                    float bb = (gc < 64) ? b0[gc] : (gc < 128) ? b1[gc - 64] : b2[gc - 128];
                    float v = acc[m][n][j] + bb;
                    if (gc < 64) v = sigmoid_f(v);
                    vp[j] = v;
                }
                *reinterpret_cast<float4*>(&((float*)o0)[(size_t)gc * 8192 + gr0]) = vv;
            } else {  // EPI 3: mix
#pragma unroll
                for (int j = 0; j < 4; ++j) {
                    const int gr = gr0 + j;
                    const size_t p = (size_t)gr * 2048 + gc;
                    float g  = bf2f(aux0[(size_t)gr * 4096 + gc]);   // gate
                    float xa = bf2f(aux1[p]);                        // xact
                    float v = acc[m][n][j] + b0[gc] + b1[gc] * xa;
                    ((u16*)o0)[p] = f2bf(v * sigmoid_f(g));
                }
            }
        }
    }
    (void)b1; (void)b2; (void)aux0; (void)aux1;
}

// ---------- depthwise causal conv (K=3) + bias + SiLU, bf16 in/out ----------
__global__ __launch_bounds__(256)
void conv_silu(const u16* __restrict__ xz, const float* __restrict__ cw,
               const float* __restrict__ cb, u16* __restrict__ xact)
{
    const size_t g  = ((size_t)blockIdx.x * 256 + threadIdx.x) * 8;
    const int    c0 = (int)(g & 2047);
    const size_t r  = g >> 11;
    const int    s  = (int)(r & (kSeq - 1));
    const u16* p = xz + r * 4096 + c0;
    u16 X0[8], X1[8] = {}, X2[8] = {};
    *reinterpret_cast<uint4*>(X0) = *reinterpret_cast<const uint4*>(p);
    if (s >= 1) *reinterpret_cast<uint4*>(X1) = *reinterpret_cast<const uint4*>(p - 4096);
    if (s >= 2) *reinterpret_cast<uint4*>(X2) = *reinterpret_cast<const uint4*>(p - 8192);
    u16 O[8];
#pragma unroll
    for (int j = 0; j < 8; ++j) {
        const int c = c0 + j;
        float v = bf2f(X2[j]) * cw[c * 3 + 0] + bf2f(X1[j]) * cw[c * 3 + 1]
                + bf2f(X0[j]) * cw[c * 3 + 2] + cb[c];
        O[j] = f2bf(v * sigmoid_f(v));
    }
    *reinterpret_cast<uint4*>(xact + r * 2048 + c0) = *reinterpret_cast<uint4*>(O);
}

// ---------- selective scan (wave-shuffle two-level) ----------
__global__ __launch_bounds__(256)
void scan_kernel(const float* __restrict__ dtbcT, float* __restrict__ y)
{
    const int b = blockIdx.x >> 6;
    const int d = blockIdx.x & 63;
    const int t = threadIdx.x;
    const int lane = t & 63;
    const int w = t >> 6;
    const size_t col = (size_t)b * kSeq + t * 16;
    const float* dtp = dtbcT + (size_t)d         * 8192 + col;
    const float* Bp  = dtbcT + (size_t)(64 + d)  * 8192 + col;
    const float* Cp  = dtbcT + (size_t)(128 + d) * 8192 + col;

    float av[16], bv[16];
    float Acc = 1.f, Bcc = 0.f;
#pragma unroll
    for (int q = 0; q < 4; ++q) {
        float4 dv = *reinterpret_cast<const float4*>(dtp + q * 4);
        float4 Bv = *reinterpret_cast<const float4*>(Bp + q * 4);
        const float* dvp = (const float*)&dv;
        const float* bvp = (const float*)&Bv;
#pragma unroll
        for (int j = 0; j < 4; ++j) {
            const int i = q * 4 + j;
            float a  = 1.f - dvp[j];
            float bb = dvp[j] * bvp[j];
            av[i] = a; bv[i] = bb;
            Acc = a * Acc;
            Bcc = a * Bcc + bb;
        }
    }

    // wave-level inclusive scan of affine transforms
#pragma unroll
    for (int off = 1; off < 64; off <<= 1) {
        float pA = __shfl_up(Acc, off, 64);
        float pB = __shfl_up(Bcc, off, 64);
        if (lane >= off) { Bcc = Acc * pB + Bcc; Acc = Acc * pA; }
    }
    __shared__ float wA[4], wB[4];
    if (lane == 63) { wA[w] = Acc; wB[w] = Bcc; }
    // lane-exclusive transform
    float eA = __shfl_up(Acc, 1, 64);
    float eB = __shfl_up(Bcc, 1, 64);
    if (lane == 0) { eA = 1.f; eB = 0.f; }
    __syncthreads();
    // state entering this wave (compose earlier waves, earliest first; s0 = 0)
    float sW = 0.f;
    for (int i = 0; i < w; ++i) sW = wA[i] * sW + wB[i];
    float s = eA * sW + eB;   // state entering this thread's 16-chunk

#pragma unroll
    for (int q = 0; q < 4; ++q) {
        float4 Cv = *reinterpret_cast<const float4*>(Cp + q * 4);
        const float* cvp = (const float*)&Cv;
#pragma unroll
        for (int j = 0; j < 4; ++j) {
            const int i = q * 4 + j;
            s = av[i] * s + bv[i];
            y[(col + i) * 64 + d] = cvp[j] * s;
        }
    }
}

// ---------- LayerNorm over 64 states -> bf16 ----------
__global__ __launch_bounds__(256)
void ln_kernel(const float* __restrict__ y, u16* __restrict__ ynb)
{
    const int w = threadIdx.x >> 6;
    const int l = threadIdx.x & 63;
    const size_t r = (size_t)blockIdx.x * 4 + w;
    float v  = y[r * 64 + l];
    float s  = v, s2 = v * v;
#pragma unroll
    for (int m = 1; m < 64; m <<= 1) {
        s  += __shfl_xor(s, m, 64);
        s2 += __shfl_xor(s2, m, 64);
    }
    float mu  = s * (1.f / 64.f);
    float var = s2 * (1.f / 64.f) - mu * mu;
    ynb[r * 64 + l] = f2bf((v - mu) * rsqrtf(var + 1e-5f));
}

}  // namespace

extern "C" void kernel_launch(void* const* d_in, const int* in_sizes, int n_in,
                              void* d_out, int out_size, void* d_ws, size_t ws_size,
                              hipStream_t stream)
{
    (void)in_sizes; (void)n_in; (void)out_size; (void)ws_size;
    const float* x     = (const float*)d_in[0];
    const float* W_in  = (const float*)d_in[1];
    const float* b_in  = (const float*)d_in[2];
    const float* cw    = (const float*)d_in[3];
    const float* cb    = (const float*)d_in[4];
    const float* W_dt  = (const float*)d_in[5];
    const float* b_dt  = (const float*)d_in[6];
    const float* W_B   = (const float*)d_in[7];
    const float* b_B   = (const float*)d_in[8];
    const float* W_C   = (const float*)d_in[9];
    const float* b_C   = (const float*)d_in[10];
    const float* W_si  = (const float*)d_in[11];
    const float* b_si  = (const float*)d_in[12];
    const float* Dv    = (const float*)d_in[13];
    const float* W_out = (const float*)d_in[14];
    const float* b_out = (const float*)d_in[15];
    float* out = (float*)d_out;

    char* ws = (char*)d_ws;
    u16*   xzb    = (u16*)  (ws);
    u16*   xb     = (u16*)  (ws + 67108864);
    u16*   xact   = (u16*)  (ws + 83886080);
    u16*   hb     = (u16*)  (ws + 117440512);
    float* dtbcT  = (float*)(ws + 150994944);
    float* ybuf   = (float*)(ws + 157286400);
    u16*   ynb    = (u16*)  (ws + 159383552);
    u16*   WinT   = (u16*)  (ws + 160432128);
    u16*   WoutT  = (u16*)  (ws + 168820736);
    u16*   WdtbcT = (u16*)  (ws + 173015040);
    u16*   WsiT   = (u16*)  (ws + 173801472);

    dim3 blk(256);
    dim3 blk512(512);

    // prep: x->bf16, all weight transposes
    convert_bf16<<<dim3((8192L * 1024 / 4 + 255) / 256), blk, 0, stream>>>(x, xb, 8192L * 1024 / 4);
    transpose_big<<<dim3(128, 32, 2), blk, 0, stream>>>(W_in, WinT, W_out, WoutT);
    transpose_small<<<dim3(2, 64, 4), blk, 0, stream>>>(W_dt, W_B, W_C, W_si, WdtbcT, WsiT);

    // xzb = bf16(x @ W_in + b_in)   [8192][4096]  (256x256 tiles, 2x4 waves)
    gemm256<256, 256, 2, 4, 1><<<dim3(32 * 16), blk512, 0, stream>>>(
        xb, WinT, b_in, xzb, 4096, 1024, 16);
    // xact = silu(causal_conv(xzb[:, :2048]))
    conv_silu<<<dim3(8192L * 2048 / (8 * 256)), blk, 0, stream>>>(xzb, cw, cb, xact);
    // dtbcT[192][8192] = [sigmoid(xact@W_dt+b) | xact@W_B+b | xact@W_C+b]^T  (single pass)
    gemm_mfma<64, 192, 2><<<dim3(128), blk, 0, stream>>>(
        xact, WdtbcT, b_dt, b_B, b_C, nullptr, nullptr, dtbcT, 192, 2048, 1);
    // y = selective_scan(dt, B, C)   [8192][64]
    scan_kernel<<<dim3(128), blk, 0, stream>>>(dtbcT, ybuf);
    // ynb = bf16(layernorm(y))
    ln_kernel<<<dim3(8192 / 4), blk, 0, stream>>>(ybuf, ynb);
    // hb = (ynb@W_si + b_si + D*xact) * sigmoid(gate)
    gemm_mfma<128, 128, 3><<<dim3(16 * 64), blk, 0, stream>>>(
        ynb, WsiT, b_si, Dv, nullptr, xzb + 2048, xact, hb, 2048, 64, 16);
    // out = hb @ W_out + b_out   (256x128 tiles, 4x2 waves)
    gemm256<256, 128, 4, 2, 0><<<dim3(32 * 8), blk512, 0, stream>>>(
        hb, WoutT, b_out, out, 1024, 2048, 8);
}

// Round 7
// 275.648 us; speedup vs baseline: 1.1259x; 1.1259x over previous
//
#include <hip/hip_runtime.h>
#include <hip/hip_bf16.h>
#include <math.h>

// SelectiveStateSpaceMixer — round 7: true counted-vmcnt phased 256-tile GEMM
// (T3+T4+T5): per-tile stage map ph1:A1(u+1) ph2:B1(u+1) ph3:B0(u+2) ph4:A0(u+2),
// single s_waitcnt vmcnt(4) per K-tile, raw s_barriers, setprio MFMA clusters.
// ws layout (bytes):
//   xzb    bf16[8192][4096]  67108864 @ 0
//   xb     bf16[8192][1024]  16777216 @ 67108864
//   xact   bf16[8192][2048]  33554432 @ 83886080
//   hb     bf16[8192][2048]  33554432 @ 117440512
//   dtbcT  f32 [192][8192]    6291456 @ 150994944
//   ybuf   f32 [8192][64]     2097152 @ 157286400
//   ynb    bf16[8192][64]     1048576 @ 159383552
//   WinT   bf16[4096][1024]   8388608 @ 160432128
//   WoutT  bf16[1024][2048]   4194304 @ 168820736
//   WdtbcT bf16[192][2048]     786432 @ 173015040
//   WsiT   bf16[2048][64]      262144 @ 173801472   end 174063616

namespace {

typedef __bf16 bf16x8 __attribute__((ext_vector_type(8)));
typedef float  f32x4  __attribute__((ext_vector_type(4)));
typedef unsigned short u16;

constexpr int kSeq = 4096;

__device__ __forceinline__ float sigmoid_f(float x) { return 1.0f / (1.0f + expf(-x)); }
__device__ __forceinline__ u16   f2bf(float f) { __bf16 h = (__bf16)f; return __builtin_bit_cast(u16, h); }
__device__ __forceinline__ float bf2f(u16 u)   { return (float)__builtin_bit_cast(__bf16, u); }

// async global->LDS, 16B per lane (dest = wave-uniform base + lane*16)
__device__ __forceinline__ void gll16(const u16* g, u16* l) {
    __builtin_amdgcn_global_load_lds(
        (const __attribute__((address_space(1))) unsigned int*)g,
        (__attribute__((address_space(3))) unsigned int*)l,
        16, 0, 0);
}

// bijective XCD-aware block swizzle (m204)
__device__ __forceinline__ int xcd_swizzle(int lin, int nwg) {
    const int q = nwg >> 3, r = nwg & 7;
    const int xcd = lin & 7, idx = lin >> 3;
    return (xcd < r ? xcd * (q + 1) : r * (q + 1) + (xcd - r) * q) + idx;
}

// ---------- fp32 -> bf16 elementwise ----------
__global__ __launch_bounds__(256)
void convert_bf16(const float* __restrict__ in, u16* __restrict__ out, long n4)
{
    long i = (long)blockIdx.x * 256 + threadIdx.x;
    if (i >= n4) return;
    float4 v = reinterpret_cast<const float4*>(in)[i];
    ushort4 o = make_ushort4(f2bf(v.x), f2bf(v.y), f2bf(v.z), f2bf(v.w));
    reinterpret_cast<ushort4*>(out)[i] = o;
}

// ---------- 32x32 tile transpose body: fp32 [R][C] -> bf16 [C][R] ----------
__device__ __forceinline__ void tr_body(float (*tile)[33],
                                        const float* __restrict__ in, u16* __restrict__ out,
                                        int R, int C, int r0, int c0, int t)
{
    const int lr = t >> 3, lc = (t & 7) * 4;
    float4 v = *reinterpret_cast<const float4*>(in + (size_t)(r0 + lr) * C + c0 + lc);
    tile[lr][lc + 0] = v.x; tile[lr][lc + 1] = v.y;
    tile[lr][lc + 2] = v.z; tile[lr][lc + 3] = v.w;
    __syncthreads();
    const int oc = t >> 3, orr = (t & 7) * 4;
    ushort4 o = make_ushort4(f2bf(tile[orr + 0][oc]), f2bf(tile[orr + 1][oc]),
                             f2bf(tile[orr + 2][oc]), f2bf(tile[orr + 3][oc]));
    *reinterpret_cast<ushort4*>(out + (size_t)(c0 + oc) * R + r0 + orr) = o;
}

__global__ __launch_bounds__(256)
void transpose_big(const float* __restrict__ Win, u16* __restrict__ WinT,
                   const float* __restrict__ Wout, u16* __restrict__ WoutT)
{
    __shared__ float tile[32][33];
    const int t = threadIdx.x;
    if (blockIdx.z == 0) {
        tr_body(tile, Win, WinT, 1024, 4096, blockIdx.y * 32, blockIdx.x * 32, t);
    } else {
        if (blockIdx.x >= 64) return;
        tr_body(tile, Wout, WoutT, 2048, 1024, blockIdx.x * 32, blockIdx.y * 32, t);
    }
}

__global__ __launch_bounds__(256)
void transpose_small(const float* __restrict__ Wdt, const float* __restrict__ WB,
                     const float* __restrict__ WC,  const float* __restrict__ Wsi,
                     u16* __restrict__ WdtbcT, u16* __restrict__ WsiT)
{
    __shared__ float tile[32][33];
    const int t = threadIdx.x;
    const int z = blockIdx.z;
    if (z < 3) {
        const float* in = (z == 0) ? Wdt : (z == 1) ? WB : WC;
        u16* out = WdtbcT + (size_t)z * 64 * 2048;
        tr_body(tile, in, out, 2048, 64, blockIdx.y * 32, blockIdx.x * 32, t);
    } else {
        tr_body(tile, Wsi, WsiT, 64, 2048, blockIdx.x * 32, blockIdx.y * 32, t);
    }
}

// ================= counted-vmcnt phased 256-tile GEMM =================
// C[M][N] = A[M][K] @ Bt[N][K]^T + bias.  BM=256, BN in {256,128}.
// 512 threads = 8 waves (2 row-groups x 4 col-groups), wave tile 128 x BN/4.
// LDS: 16KB half-tile units, double buffered. XOR-swizzled (R5-proven, 0 conflicts).
// Per K-tile u: 4 phases, each {stage-issue | ds_read quadrant ops | s_barrier |
// setprio+16 MFMA+setprio | s_barrier}; ONE counted vmcnt(4) at ph4 (never 0
// except the last two tiles). Quadrants (0,0)->(0,1)->(1,1)->(1,0); bg0 regs
// stay live through ph4 so B0's LDS slot is free for ph3's stage.
#define READ_A(MH)                                                        \
    _Pragma("unroll")                                                     \
    for (int m = 0; m < 4; ++m) {                                         \
        const int rb = (((MH) * 4 + m) * 16 + fr) * 64;                   \
        _Pragma("unroll")                                                 \
        for (int kk = 0; kk < 2; ++kk)                                    \
            af[m][kk] = *reinterpret_cast<const bf16x8*>(                 \
                &As[cur][wrow][0] + rb + (((kk * 4 + fq) * 8) ^ frx));    \
    }

#define READ_B(DST, NH)                                                   \
    _Pragma("unroll")                                                     \
    for (int n = 0; n < FNH; ++n) {                                       \
        const int rb = (rbB + ((NH) * FNH + n) * 16 + fr) * 64;           \
        _Pragma("unroll")                                                 \
        for (int kk = 0; kk < 2; ++kk)                                    \
            DST[n][kk] = *reinterpret_cast<const bf16x8*>(                \
                &Bs[cur][hb][0] + rb + (((kk * 4 + fq) * 8) ^ frx));      \
    }

#define MMAQ(MH, NH, BG)                                                  \
    __builtin_amdgcn_s_setprio(1);                                        \
    _Pragma("unroll")                                                     \
    for (int m = 0; m < 4; ++m)                                           \
        _Pragma("unroll")                                                 \
        for (int n = 0; n < FNH; ++n)                                     \
            _Pragma("unroll")                                             \
            for (int kk = 0; kk < 2; ++kk)                                \
                acc[(MH) * 4 + m][(NH) * FNH + n] =                       \
                    __builtin_amdgcn_mfma_f32_16x16x32_bf16(              \
                        af[m][kk], BG[n][kk],                             \
                        acc[(MH) * 4 + m][(NH) * FNH + n], 0, 0, 0);      \
    __builtin_amdgcn_s_setprio(0);

template <int BN, int EPI>   // EPI 0: fp32 out; EPI 1: bf16 out
__global__ __launch_bounds__(512, 2)
void gemm256(const u16* __restrict__ A, const u16* __restrict__ Bt,
             const float* __restrict__ b0, void* __restrict__ o0,
             int N, int K, int nbx)
{
    constexpr int FN  = BN / 64;      // frags per wave in N (4 or 2)
    constexpr int FNH = FN / 2;       // per-quadrant (2 or 1)
    constexpr int NB  = BN / 128;     // B half-tile units per K-tile (2 or 1)
    constexpr int HSZ = 128 * 64;     // u16 per 16KB half-tile

    __shared__ __align__(16) u16 As[2][2][HSZ];
    __shared__ __align__(16) u16 Bs[2][NB][HSZ];

    const int tid  = threadIdx.x;
    const int lane = tid & 63;
    const int wid  = tid >> 6;
    const int wrow = wid >> 2;        // A half this wave reads
    const int wcol = wid & 3;
    const int swz  = xcd_swizzle(blockIdx.x, gridDim.x);
    const int row0 = (swz / nbx) * 256;
    const int col0 = (swz % nbx) * BN;

    const int srow = lane >> 3;
    const int scol = ((lane & 7) ^ srow) * 8;     // pre-swizzled global col
    const int fr   = lane & 15;
    const int fq   = lane >> 4;
    const int frx  = (fr & 7) * 8;                // read-side swizzle XOR
    const int nt   = K / 64;

    const int hb  = (NB == 2) ? (wcol >> 1) : 0;            // B half this wave reads
    const int rbB = (NB == 2) ? ((wcol & 1) * 64) : (wcol * 32);  // row base in half

    auto stageA = [&](int u, int h) {
        u16* dst = &As[u & 1][h][0] + wid * 1024 + lane * 8;
        const u16* src = A + (size_t)(row0 + h * 128 + wid * 16 + srow) * K + u * 64 + scol;
        gll16(src, dst);
        gll16(src + (size_t)8 * K, dst + 512);
    };
    auto stageB = [&](int u, int h) {
        u16* dst = &Bs[u & 1][h][0] + wid * 1024 + lane * 8;
        const u16* src = Bt + (size_t)(col0 + h * 128 + wid * 16 + srow) * K + u * 64 + scol;
        gll16(src, dst);
        gll16(src + (size_t)8 * K, dst + 512);
    };

    f32x4 acc[8][FN];
#pragma unroll
    for (int m = 0; m < 8; ++m)
#pragma unroll
        for (int n = 0; n < FN; ++n) acc[m][n] = (f32x4){0.f, 0.f, 0.f, 0.f};

    // prologue: tile0 complete + B0/A0 of tile1; counted wait leaves those 4 in flight
    stageA(0, 0); stageB(0, 0);
    if (NB == 2) stageB(0, 1);
    stageA(0, 1);
    if (nt > 1) { stageB(1, 0); stageA(1, 0); }
    if (nt > 1) asm volatile("s_waitcnt vmcnt(4)" ::: "memory");
    else        asm volatile("s_waitcnt vmcnt(0)" ::: "memory");
    __builtin_amdgcn_s_barrier();

    bf16x8 af[4][2], bg0[FNH][2], bg1[FNH][2];

    for (int u = 0; u < nt; ++u) {
        const int cur = u & 1;
        // ---- phase 1: quadrant (0,0); stage A1(u+1) [other buffer]
        if (u + 1 < nt) stageA(u + 1, 1);
        READ_A(0)
        READ_B(bg0, 0)
        __builtin_amdgcn_s_barrier();
        MMAQ(0, 0, bg0)
        __builtin_amdgcn_s_barrier();
        // ---- phase 2: quadrant (0,1); stage B1(u+1) [other buffer]
        if (NB == 2 && u + 1 < nt) stageB(u + 1, 1);
        READ_B(bg1, 1)
        __builtin_amdgcn_s_barrier();
        MMAQ(0, 1, bg1)
        __builtin_amdgcn_s_barrier();
        // ---- phase 3: quadrant (1,1); stage B0(u+2) [cur buffer, B0 reads done ph2]
        if (u + 2 < nt) stageB(u + 2, 0);
        READ_A(1)
        __builtin_amdgcn_s_barrier();
        MMAQ(1, 1, bg1)
        __builtin_amdgcn_s_barrier();
        // ---- phase 4: quadrant (1,0) from live bg0 regs; stage A0(u+2) [A reads done ph3]
        if (u + 2 < nt) stageA(u + 2, 0);
        __builtin_amdgcn_s_barrier();
        MMAQ(1, 0, bg0)
        // counted drain: 4 newest (ph3+ph4 stages) may stay in flight;
        // everything through B1(u+1) has landed -> next tile's buffer ready
        if (u + 2 < nt) asm volatile("s_waitcnt vmcnt(4)" ::: "memory");
        else            asm volatile("s_waitcnt vmcnt(0)" ::: "memory");
        __builtin_amdgcn_s_barrier();
    }

    // epilogue
#pragma unroll
    for (int m = 0; m < 8; ++m) {
#pragma unroll
        for (int n = 0; n < FN; ++n) {
            const int gc  = col0 + wcol * (BN / 4) + n * 16 + fr;
            const int gr0 = row0 + wrow * 128 + m * 16 + fq * 4;
#pragma unroll
            for (int j = 0; j < 4; ++j) {
                const float v = acc[m][n][j] + b0[gc];
                if constexpr (EPI == 0) {
                    ((float*)o0)[(size_t)(gr0 + j) * N + gc] = v;
                } else {
                    ((u16*)o0)[(size_t)(gr0 + j) * N + gc] = f2bf(v);
                }
            }
        }
    }
}
#undef READ_A
#undef READ_B
#undef MMAQ

// ---------- 4-wave 2-barrier MFMA GEMM (dtbc / mix epilogues) ----------
// EPI 2: fp32 TRANSPOSED out [N][8192]; bias b0|b1|b2 per 64-col; sigmoid col<64
// EPI 3: mix: bf16 out = (acc + b_si + D*xact) * sigmoid(gate)
template <int BM, int BN, int EPI>
__global__ __launch_bounds__(256)
void gemm_mfma(const u16* __restrict__ A, const u16* __restrict__ Bt,
               const float* __restrict__ b0, const float* __restrict__ b1,
               const float* __restrict__ b2,
               const u16* __restrict__ aux0, const u16* __restrict__ aux1,
               void* __restrict__ o0, int N, int K, int nbx)
{
    constexpr int FM = BM / 32, FN = BN / 32;
    constexpr int CA = BM / 32, CB = BN / 32;
    __shared__ __align__(16) u16 As[BM][64];
    __shared__ __align__(16) u16 Bs[BN][64];

    const int tid  = threadIdx.x;
    const int lane = tid & 63;
    const int wid  = tid >> 6;
    const int wr   = (wid >> 1) * (BM / 2);
    const int wc   = (wid & 1)  * (BN / 2);
    const int swz  = xcd_swizzle(blockIdx.x, gridDim.x);
    const int row0 = (swz / nbx) * BM;
    const int col0 = (swz % nbx) * BN;

    const int srow = lane >> 3;
    const int scol = ((lane & 7) ^ srow) * 8;
    const int fr   = lane & 15;
    const int fq   = lane >> 4;

    f32x4 acc[FM][FN];
#pragma unroll
    for (int m = 0; m < FM; ++m)
#pragma unroll
        for (int n = 0; n < FN; ++n) acc[m][n] = (f32x4){0.f, 0.f, 0.f, 0.f};

    for (int k0 = 0; k0 < K; k0 += 64) {
#pragma unroll
        for (int i = 0; i < CA; ++i) {
            const int c = wid * CA + i;
            gll16(A + (size_t)(row0 + c * 8 + srow) * K + k0 + scol,
                  &As[0][0] + c * 512 + lane * 8);
        }
#pragma unroll
        for (int i = 0; i < CB; ++i) {
            const int c = wid * CB + i;
            gll16(Bt + (size_t)(col0 + c * 8 + srow) * K + k0 + scol,
                  &Bs[0][0] + c * 512 + lane * 8);
        }
        __syncthreads();
#pragma unroll
        for (int kk = 0; kk < 2; ++kk) {
            bf16x8 af[FM], bg[FN];
#pragma unroll
            for (int m = 0; m < FM; ++m) {
                const int rr = wr + m * 16 + fr;
                af[m] = *reinterpret_cast<const bf16x8*>(
                    &As[rr][(kk * 32 + fq * 8) ^ ((rr & 7) * 8)]);
            }
#pragma unroll
            for (int n = 0; n < FN; ++n) {
                const int rr = wc + n * 16 + fr;
                bg[n] = *reinterpret_cast<const bf16x8*>(
                    &Bs[rr][(kk * 32 + fq * 8) ^ ((rr & 7) * 8)]);
            }
#pragma unroll
            for (int m = 0; m < FM; ++m)
#pragma unroll
                for (int n = 0; n < FN; ++n)
                    acc[m][n] = __builtin_amdgcn_mfma_f32_16x16x32_bf16(af[m], bg[n], acc[m][n], 0, 0, 0);
        }
        __syncthreads();
    }

#pragma unroll
    for (int m = 0; m < FM; ++m) {
#pragma unroll
        for (int n = 0; n < FN; ++n) {
            const int gc  = col0 + wc + n * 16 + fr;
            const int gr0 = row0 + wr + m * 16 + fq * 4;
            if constexpr (EPI == 2) {
                float4 vv;
                float* vp = (float*)&vv;
#pragma unroll
                for (int j = 0; j < 4; ++j) {
                    float bb = (gc < 64) ? b0[gc] : (gc < 128) ? b1[gc - 64] : b2[gc - 128];
                    float v = acc[m][n][j] + bb;
                    if (gc < 64) v = sigmoid_f(v);
                    vp[j] = v;
                }
                *reinterpret_cast<float4*>(&((float*)o0)[(size_t)gc * 8192 + gr0]) = vv;
            } else {  // EPI 3: mix
#pragma unroll
                for (int j = 0; j < 4; ++j) {
                    const int gr = gr0 + j;
                    const size_t p = (size_t)gr * 2048 + gc;
                    float g  = bf2f(aux0[(size_t)gr * 4096 + gc]);   // gate
                    float xa = bf2f(aux1[p]);                        // xact
                    float v = acc[m][n][j] + b0[gc] + b1[gc] * xa;
                    ((u16*)o0)[p] = f2bf(v * sigmoid_f(g));
                }
            }
        }
    }
    (void)b1; (void)b2; (void)aux0; (void)aux1;
}

// ---------- depthwise causal conv (K=3) + bias + SiLU, bf16 in/out ----------
__global__ __launch_bounds__(256)
void conv_silu(const u16* __restrict__ xz, const float* __restrict__ cw,
               const float* __restrict__ cb, u16* __restrict__ xact)
{
    const size_t g  = ((size_t)blockIdx.x * 256 + threadIdx.x) * 8;
    const int    c0 = (int)(g & 2047);
    const size_t r  = g >> 11;
    const int    s  = (int)(r & (kSeq - 1));
    const u16* p = xz + r * 4096 + c0;
    u16 X0[8], X1[8] = {}, X2[8] = {};
    *reinterpret_cast<uint4*>(X0) = *reinterpret_cast<const uint4*>(p);
    if (s >= 1) *reinterpret_cast<uint4*>(X1) = *reinterpret_cast<const uint4*>(p - 4096);
    if (s >= 2) *reinterpret_cast<uint4*>(X2) = *reinterpret_cast<const uint4*>(p - 8192);
    u16 O[8];
#pragma unroll
    for (int j = 0; j < 8; ++j) {
        const int c = c0 + j;
        float v = bf2f(X2[j]) * cw[c * 3 + 0] + bf2f(X1[j]) * cw[c * 3 + 1]
                + bf2f(X0[j]) * cw[c * 3 + 2] + cb[c];
        O[j] = f2bf(v * sigmoid_f(v));
    }
    *reinterpret_cast<uint4*>(xact + r * 2048 + c0) = *reinterpret_cast<uint4*>(O);
}

// ---------- selective scan (wave-shuffle two-level) ----------
__global__ __launch_bounds__(256)
void scan_kernel(const float* __restrict__ dtbcT, float* __restrict__ y)
{
    const int b = blockIdx.x >> 6;
    const int d = blockIdx.x & 63;
    const int t = threadIdx.x;
    const int lane = t & 63;
    const int w = t >> 6;
    const size_t col = (size_t)b * kSeq + t * 16;
    const float* dtp = dtbcT + (size_t)d         * 8192 + col;
    const float* Bp  = dtbcT + (size_t)(64 + d)  * 8192 + col;
    const float* Cp  = dtbcT + (size_t)(128 + d) * 8192 + col;

    float av[16], bv[16];
    float Acc = 1.f, Bcc = 0.f;
#pragma unroll
    for (int q = 0; q < 4; ++q) {
        float4 dv = *reinterpret_cast<const float4*>(dtp + q * 4);
        float4 Bv = *reinterpret_cast<const float4*>(Bp + q * 4);
        const float* dvp = (const float*)&dv;
        const float* bvp = (const float*)&Bv;
#pragma unroll
        for (int j = 0; j < 4; ++j) {
            const int i = q * 4 + j;
            float a  = 1.f - dvp[j];
            float bb = dvp[j] * bvp[j];
            av[i] = a; bv[i] = bb;
            Acc = a * Acc;
            Bcc = a * Bcc + bb;
        }
    }

#pragma unroll
    for (int off = 1; off < 64; off <<= 1) {
        float pA = __shfl_up(Acc, off, 64);
        float pB = __shfl_up(Bcc, off, 64);
        if (lane >= off) { Bcc = Acc * pB + Bcc; Acc = Acc * pA; }
    }
    __shared__ float wA[4], wB[4];
    if (lane == 63) { wA[w] = Acc; wB[w] = Bcc; }
    float eA = __shfl_up(Acc, 1, 64);
    float eB = __shfl_up(Bcc, 1, 64);
    if (lane == 0) { eA = 1.f; eB = 0.f; }
    __syncthreads();
    float sW = 0.f;
    for (int i = 0; i < w; ++i) sW = wA[i] * sW + wB[i];
    float s = eA * sW + eB;

#pragma unroll
    for (int q = 0; q < 4; ++q) {
        float4 Cv = *reinterpret_cast<const float4*>(Cp + q * 4);
        const float* cvp = (const float*)&Cv;
#pragma unroll
        for (int j = 0; j < 4; ++j) {
            const int i = q * 4 + j;
            s = av[i] * s + bv[i];
            y[(col + i) * 64 + d] = cvp[j] * s;
        }
    }
}

// ---------- LayerNorm over 64 states -> bf16 ----------
__global__ __launch_bounds__(256)
void ln_kernel(const float* __restrict__ y, u16* __restrict__ ynb)
{
    const int w = threadIdx.x >> 6;
    const int l = threadIdx.x & 63;
    const size_t r = (size_t)blockIdx.x * 4 + w;
    float v  = y[r * 64 + l];
    float s  = v, s2 = v * v;
#pragma unroll
    for (int m = 1; m < 64; m <<= 1) {
        s  += __shfl_xor(s, m, 64);
        s2 += __shfl_xor(s2, m, 64);
    }
    float mu  = s * (1.f / 64.f);
    float var = s2 * (1.f / 64.f) - mu * mu;
    ynb[r * 64 + l] = f2bf((v - mu) * rsqrtf(var + 1e-5f));
}

}  // namespace

extern "C" void kernel_launch(void* const* d_in, const int* in_sizes, int n_in,
                              void* d_out, int out_size, void* d_ws, size_t ws_size,
                              hipStream_t stream)
{
    (void)in_sizes; (void)n_in; (void)out_size; (void)ws_size;
    const float* x     = (const float*)d_in[0];
    const float* W_in  = (const float*)d_in[1];
    const float* b_in  = (const float*)d_in[2];
    const float* cw    = (const float*)d_in[3];
    const float* cb    = (const float*)d_in[4];
    const float* W_dt  = (const float*)d_in[5];
    const float* b_dt  = (const float*)d_in[6];
    const float* W_B   = (const float*)d_in[7];
    const float* b_B   = (const float*)d_in[8];
    const float* W_C   = (const float*)d_in[9];
    const float* b_C   = (const float*)d_in[10];
    const float* W_si  = (const float*)d_in[11];
    const float* b_si  = (const float*)d_in[12];
    const float* Dv    = (const float*)d_in[13];
    const float* W_out = (const float*)d_in[14];
    const float* b_out = (const float*)d_in[15];
    float* out = (float*)d_out;

    char* ws = (char*)d_ws;
    u16*   xzb    = (u16*)  (ws);
    u16*   xb     = (u16*)  (ws + 67108864);
    u16*   xact   = (u16*)  (ws + 83886080);
    u16*   hb     = (u16*)  (ws + 117440512);
    float* dtbcT  = (float*)(ws + 150994944);
    float* ybuf   = (float*)(ws + 157286400);
    u16*   ynb    = (u16*)  (ws + 159383552);
    u16*   WinT   = (u16*)  (ws + 160432128);
    u16*   WoutT  = (u16*)  (ws + 168820736);
    u16*   WdtbcT = (u16*)  (ws + 173015040);
    u16*   WsiT   = (u16*)  (ws + 173801472);

    dim3 blk(256);
    dim3 blk512(512);

    // prep: x->bf16, all weight transposes
    convert_bf16<<<dim3((8192L * 1024 / 4 + 255) / 256), blk, 0, stream>>>(x, xb, 8192L * 1024 / 4);
    transpose_big<<<dim3(128, 32, 2), blk, 0, stream>>>(W_in, WinT, W_out, WoutT);
    transpose_small<<<dim3(2, 64, 4), blk, 0, stream>>>(W_dt, W_B, W_C, W_si, WdtbcT, WsiT);

    // xzb = bf16(x @ W_in + b_in)   [8192][4096]  (256x256 tiles)
    gemm256<256, 1><<<dim3(32 * 16), blk512, 0, stream>>>(
        xb, WinT, b_in, xzb, 4096, 1024, 16);
    // xact = silu(causal_conv(xzb[:, :2048]))
    conv_silu<<<dim3(8192L * 2048 / (8 * 256)), blk, 0, stream>>>(xzb, cw, cb, xact);
    // dtbcT[192][8192] = [sigmoid(xact@W_dt+b) | xact@W_B+b | xact@W_C+b]^T
    gemm_mfma<64, 192, 2><<<dim3(128), blk, 0, stream>>>(
        xact, WdtbcT, b_dt, b_B, b_C, nullptr, nullptr, dtbcT, 192, 2048, 1);
    // y = selective_scan(dt, B, C)   [8192][64]
    scan_kernel<<<dim3(128), blk, 0, stream>>>(dtbcT, ybuf);
    // ynb = bf16(layernorm(y))
    ln_kernel<<<dim3(8192 / 4), blk, 0, stream>>>(ybuf, ynb);
    // hb = (ynb@W_si + b_si + D*xact) * sigmoid(gate)
    gemm_mfma<128, 128, 3><<<dim3(16 * 64), blk, 0, stream>>>(
        ynb, WsiT, b_si, Dv, nullptr, xzb + 2048, xact, hb, 2048, 64, 16);
    // out = hb @ W_out + b_out   (256x128 tiles, full 256-block grid)
    gemm256<128, 0><<<dim3(32 * 8), blk512, 0, stream>>>(
        hb, WoutT, b_out, out, 1024, 2048, 8);
}

// Round 8
// 246.665 us; speedup vs baseline: 1.2582x; 1.1175x over previous
//
#include <hip/hip_runtime.h>
#include <hip/hip_bf16.h>
#include <math.h>

// SelectiveStateSpaceMixer — round 8: consolidate. Both big GEMMs on the
// R5-proven 2-barrier 128x128 BK=64 XOR-swizzled gll16 kernel; dtbc widened
// to 256 blocks (BM=32); shuffle scan (R6-proven).
// ws layout (bytes):
//   xzb    bf16[8192][4096]  67108864 @ 0
//   xb     bf16[8192][1024]  16777216 @ 67108864
//   xact   bf16[8192][2048]  33554432 @ 83886080
//   hb     bf16[8192][2048]  33554432 @ 117440512
//   dtbcT  f32 [192][8192]    6291456 @ 150994944
//   ybuf   f32 [8192][64]     2097152 @ 157286400
//   ynb    bf16[8192][64]     1048576 @ 159383552
//   WinT   bf16[4096][1024]   8388608 @ 160432128
//   WoutT  bf16[1024][2048]   4194304 @ 168820736
//   WdtbcT bf16[192][2048]     786432 @ 173015040
//   WsiT   bf16[2048][64]      262144 @ 173801472   end 174063616

namespace {

typedef __bf16 bf16x8 __attribute__((ext_vector_type(8)));
typedef float  f32x4  __attribute__((ext_vector_type(4)));
typedef unsigned short u16;

constexpr int kSeq = 4096;

__device__ __forceinline__ float sigmoid_f(float x) { return 1.0f / (1.0f + expf(-x)); }
__device__ __forceinline__ u16   f2bf(float f) { __bf16 h = (__bf16)f; return __builtin_bit_cast(u16, h); }
__device__ __forceinline__ float bf2f(u16 u)   { return (float)__builtin_bit_cast(__bf16, u); }

// async global->LDS, 16B per lane (dest = wave-uniform base + lane*16)
__device__ __forceinline__ void gll16(const u16* g, u16* l) {
    __builtin_amdgcn_global_load_lds(
        (const __attribute__((address_space(1))) unsigned int*)g,
        (__attribute__((address_space(3))) unsigned int*)l,
        16, 0, 0);
}

// bijective XCD-aware block swizzle (m204)
__device__ __forceinline__ int xcd_swizzle(int lin, int nwg) {
    const int q = nwg >> 3, r = nwg & 7;
    const int xcd = lin & 7, idx = lin >> 3;
    return (xcd < r ? xcd * (q + 1) : r * (q + 1) + (xcd - r) * q) + idx;
}

// ---------- fp32 -> bf16 elementwise ----------
__global__ __launch_bounds__(256)
void convert_bf16(const float* __restrict__ in, u16* __restrict__ out, long n4)
{
    long i = (long)blockIdx.x * 256 + threadIdx.x;
    if (i >= n4) return;
    float4 v = reinterpret_cast<const float4*>(in)[i];
    ushort4 o = make_ushort4(f2bf(v.x), f2bf(v.y), f2bf(v.z), f2bf(v.w));
    reinterpret_cast<ushort4*>(out)[i] = o;
}

// ---------- 32x32 tile transpose body: fp32 [R][C] -> bf16 [C][R] ----------
__device__ __forceinline__ void tr_body(float (*tile)[33],
                                        const float* __restrict__ in, u16* __restrict__ out,
                                        int R, int C, int r0, int c0, int t)
{
    const int lr = t >> 3, lc = (t & 7) * 4;
    float4 v = *reinterpret_cast<const float4*>(in + (size_t)(r0 + lr) * C + c0 + lc);
    tile[lr][lc + 0] = v.x; tile[lr][lc + 1] = v.y;
    tile[lr][lc + 2] = v.z; tile[lr][lc + 3] = v.w;
    __syncthreads();
    const int oc = t >> 3, orr = (t & 7) * 4;
    ushort4 o = make_ushort4(f2bf(tile[orr + 0][oc]), f2bf(tile[orr + 1][oc]),
                             f2bf(tile[orr + 2][oc]), f2bf(tile[orr + 3][oc]));
    *reinterpret_cast<ushort4*>(out + (size_t)(c0 + oc) * R + r0 + orr) = o;
}

__global__ __launch_bounds__(256)
void transpose_big(const float* __restrict__ Win, u16* __restrict__ WinT,
                   const float* __restrict__ Wout, u16* __restrict__ WoutT)
{
    __shared__ float tile[32][33];
    const int t = threadIdx.x;
    if (blockIdx.z == 0) {
        tr_body(tile, Win, WinT, 1024, 4096, blockIdx.y * 32, blockIdx.x * 32, t);
    } else {
        if (blockIdx.x >= 64) return;
        tr_body(tile, Wout, WoutT, 2048, 1024, blockIdx.x * 32, blockIdx.y * 32, t);
    }
}

__global__ __launch_bounds__(256)
void transpose_small(const float* __restrict__ Wdt, const float* __restrict__ WB,
                     const float* __restrict__ WC,  const float* __restrict__ Wsi,
                     u16* __restrict__ WdtbcT, u16* __restrict__ WsiT)
{
    __shared__ float tile[32][33];
    const int t = threadIdx.x;
    const int z = blockIdx.z;
    if (z < 3) {
        const float* in = (z == 0) ? Wdt : (z == 1) ? WB : WC;
        u16* out = WdtbcT + (size_t)z * 64 * 2048;
        tr_body(tile, in, out, 2048, 64, blockIdx.y * 32, blockIdx.x * 32, t);
    } else {
        tr_body(tile, Wsi, WsiT, 64, 2048, blockIdx.x * 32, blockIdx.y * 32, t);
    }
}

// ---------- 4-wave 2-barrier MFMA GEMM: C[M][N] = A[M][K] @ Bt[N][K]^T ----------
// BK=64, linear-LDS global_load_lds w16, both-sides XOR swizzle (0 conflicts).
// EPI 0: fp32 out ldc=N           (gemm_out)
// EPI 1: bf16 out ldc=N           (gemm_in -> xzb)
// EPI 2: fp32 TRANSPOSED out [N][8192]; bias b0|b1|b2 per 64-col; sigmoid col<64
// EPI 3: mix: bf16 out = (acc + b_si + D*xact) * sigmoid(gate)
template <int BM, int BN, int EPI>
__global__ __launch_bounds__(256)
void gemm_mfma(const u16* __restrict__ A, const u16* __restrict__ Bt,
               const float* __restrict__ b0, const float* __restrict__ b1,
               const float* __restrict__ b2,
               const u16* __restrict__ aux0, const u16* __restrict__ aux1,
               void* __restrict__ o0, int N, int K, int nbx)
{
    constexpr int FM = BM / 32, FN = BN / 32;
    constexpr int CA = BM / 32, CB = BN / 32;
    __shared__ __align__(16) u16 As[BM][64];
    __shared__ __align__(16) u16 Bs[BN][64];

    const int tid  = threadIdx.x;
    const int lane = tid & 63;
    const int wid  = tid >> 6;
    const int wr   = (wid >> 1) * (BM / 2);
    const int wc   = (wid & 1)  * (BN / 2);
    const int swz  = xcd_swizzle(blockIdx.x, gridDim.x);
    const int row0 = (swz / nbx) * BM;
    const int col0 = (swz % nbx) * BN;

    const int srow = lane >> 3;
    const int scol = ((lane & 7) ^ srow) * 8;   // pre-swizzled global col
    const int fr   = lane & 15;
    const int fq   = lane >> 4;

    f32x4 acc[FM][FN];
#pragma unroll
    for (int m = 0; m < FM; ++m)
#pragma unroll
        for (int n = 0; n < FN; ++n) acc[m][n] = (f32x4){0.f, 0.f, 0.f, 0.f};

    for (int k0 = 0; k0 < K; k0 += 64) {
#pragma unroll
        for (int i = 0; i < CA; ++i) {
            const int c = wid * CA + i;
            gll16(A + (size_t)(row0 + c * 8 + srow) * K + k0 + scol,
                  &As[0][0] + c * 512 + lane * 8);
        }
#pragma unroll
        for (int i = 0; i < CB; ++i) {
            const int c = wid * CB + i;
            gll16(Bt + (size_t)(col0 + c * 8 + srow) * K + k0 + scol,
                  &Bs[0][0] + c * 512 + lane * 8);
        }
        __syncthreads();
#pragma unroll
        for (int kk = 0; kk < 2; ++kk) {
            bf16x8 af[FM], bg[FN];
#pragma unroll
            for (int m = 0; m < FM; ++m) {
                const int rr = wr + m * 16 + fr;
                af[m] = *reinterpret_cast<const bf16x8*>(
                    &As[rr][(kk * 32 + fq * 8) ^ ((rr & 7) * 8)]);
            }
#pragma unroll
            for (int n = 0; n < FN; ++n) {
                const int rr = wc + n * 16 + fr;
                bg[n] = *reinterpret_cast<const bf16x8*>(
                    &Bs[rr][(kk * 32 + fq * 8) ^ ((rr & 7) * 8)]);
            }
#pragma unroll
            for (int m = 0; m < FM; ++m)
#pragma unroll
                for (int n = 0; n < FN; ++n)
                    acc[m][n] = __builtin_amdgcn_mfma_f32_16x16x32_bf16(af[m], bg[n], acc[m][n], 0, 0, 0);
        }
        __syncthreads();
    }

#pragma unroll
    for (int m = 0; m < FM; ++m) {
#pragma unroll
        for (int n = 0; n < FN; ++n) {
            const int gc  = col0 + wc + n * 16 + fr;
            const int gr0 = row0 + wr + m * 16 + fq * 4;
            if constexpr (EPI == 2) {
                float4 vv;
                float* vp = (float*)&vv;
#pragma unroll
                for (int j = 0; j < 4; ++j) {
                    float bb = (gc < 64) ? b0[gc] : (gc < 128) ? b1[gc - 64] : b2[gc - 128];
                    float v = acc[m][n][j] + bb;
                    if (gc < 64) v = sigmoid_f(v);
                    vp[j] = v;
                }
                *reinterpret_cast<float4*>(&((float*)o0)[(size_t)gc * 8192 + gr0]) = vv;
            } else {
#pragma unroll
                for (int j = 0; j < 4; ++j) {
                    const int gr = gr0 + j;
                    float v = acc[m][n][j];
                    if constexpr (EPI == 0) {
                        ((float*)o0)[(size_t)gr * N + gc] = v + b0[gc];
                    } else if constexpr (EPI == 1) {
                        ((u16*)o0)[(size_t)gr * N + gc] = f2bf(v + b0[gc]);
                    } else {  // EPI 3: mix
                        const size_t p = (size_t)gr * 2048 + gc;
                        float g  = bf2f(aux0[(size_t)gr * 4096 + gc]);   // gate
                        float xa = bf2f(aux1[p]);                        // xact
                        v = v + b0[gc] + b1[gc] * xa;
                        ((u16*)o0)[p] = f2bf(v * sigmoid_f(g));
                    }
                }
            }
        }
    }
    (void)b1; (void)b2; (void)aux0; (void)aux1;
}

// ---------- depthwise causal conv (K=3) + bias + SiLU, bf16 in/out ----------
__global__ __launch_bounds__(256)
void conv_silu(const u16* __restrict__ xz, const float* __restrict__ cw,
               const float* __restrict__ cb, u16* __restrict__ xact)
{
    const size_t g  = ((size_t)blockIdx.x * 256 + threadIdx.x) * 8;
    const int    c0 = (int)(g & 2047);
    const size_t r  = g >> 11;
    const int    s  = (int)(r & (kSeq - 1));
    const u16* p = xz + r * 4096 + c0;
    u16 X0[8], X1[8] = {}, X2[8] = {};
    *reinterpret_cast<uint4*>(X0) = *reinterpret_cast<const uint4*>(p);
    if (s >= 1) *reinterpret_cast<uint4*>(X1) = *reinterpret_cast<const uint4*>(p - 4096);
    if (s >= 2) *reinterpret_cast<uint4*>(X2) = *reinterpret_cast<const uint4*>(p - 8192);
    u16 O[8];
#pragma unroll
    for (int j = 0; j < 8; ++j) {
        const int c = c0 + j;
        float v = bf2f(X2[j]) * cw[c * 3 + 0] + bf2f(X1[j]) * cw[c * 3 + 1]
                + bf2f(X0[j]) * cw[c * 3 + 2] + cb[c];
        O[j] = f2bf(v * sigmoid_f(v));
    }
    *reinterpret_cast<uint4*>(xact + r * 2048 + c0) = *reinterpret_cast<uint4*>(O);
}

// ---------- selective scan (wave-shuffle two-level) ----------
__global__ __launch_bounds__(256)
void scan_kernel(const float* __restrict__ dtbcT, float* __restrict__ y)
{
    const int b = blockIdx.x >> 6;
    const int d = blockIdx.x & 63;
    const int t = threadIdx.x;
    const int lane = t & 63;
    const int w = t >> 6;
    const size_t col = (size_t)b * kSeq + t * 16;
    const float* dtp = dtbcT + (size_t)d         * 8192 + col;
    const float* Bp  = dtbcT + (size_t)(64 + d)  * 8192 + col;
    const float* Cp  = dtbcT + (size_t)(128 + d) * 8192 + col;

    float av[16], bv[16];
    float Acc = 1.f, Bcc = 0.f;
#pragma unroll
    for (int q = 0; q < 4; ++q) {
        float4 dv = *reinterpret_cast<const float4*>(dtp + q * 4);
        float4 Bv = *reinterpret_cast<const float4*>(Bp + q * 4);
        const float* dvp = (const float*)&dv;
        const float* bvp = (const float*)&Bv;
#pragma unroll
        for (int j = 0; j < 4; ++j) {
            const int i = q * 4 + j;
            float a  = 1.f - dvp[j];
            float bb = dvp[j] * bvp[j];
            av[i] = a; bv[i] = bb;
            Acc = a * Acc;
            Bcc = a * Bcc + bb;
        }
    }

#pragma unroll
    for (int off = 1; off < 64; off <<= 1) {
        float pA = __shfl_up(Acc, off, 64);
        float pB = __shfl_up(Bcc, off, 64);
        if (lane >= off) { Bcc = Acc * pB + Bcc; Acc = Acc * pA; }
    }
    __shared__ float wA[4], wB[4];
    if (lane == 63) { wA[w] = Acc; wB[w] = Bcc; }
    float eA = __shfl_up(Acc, 1, 64);
    float eB = __shfl_up(Bcc, 1, 64);
    if (lane == 0) { eA = 1.f; eB = 0.f; }
    __syncthreads();
    float sW = 0.f;
    for (int i = 0; i < w; ++i) sW = wA[i] * sW + wB[i];
    float s = eA * sW + eB;

#pragma unroll
    for (int q = 0; q < 4; ++q) {
        float4 Cv = *reinterpret_cast<const float4*>(Cp + q * 4);
        const float* cvp = (const float*)&Cv;
#pragma unroll
        for (int j = 0; j < 4; ++j) {
            const int i = q * 4 + j;
            s = av[i] * s + bv[i];
            y[(col + i) * 64 + d] = cvp[j] * s;
        }
    }
}

// ---------- LayerNorm over 64 states -> bf16 ----------
__global__ __launch_bounds__(256)
void ln_kernel(const float* __restrict__ y, u16* __restrict__ ynb)
{
    const int w = threadIdx.x >> 6;
    const int l = threadIdx.x & 63;
    const size_t r = (size_t)blockIdx.x * 4 + w;
    float v  = y[r * 64 + l];
    float s  = v, s2 = v * v;
#pragma unroll
    for (int m = 1; m < 64; m <<= 1) {
        s  += __shfl_xor(s, m, 64);
        s2 += __shfl_xor(s2, m, 64);
    }
    float mu  = s * (1.f / 64.f);
    float var = s2 * (1.f / 64.f) - mu * mu;
    ynb[r * 64 + l] = f2bf((v - mu) * rsqrtf(var + 1e-5f));
}

}  // namespace

extern "C" void kernel_launch(void* const* d_in, const int* in_sizes, int n_in,
                              void* d_out, int out_size, void* d_ws, size_t ws_size,
                              hipStream_t stream)
{
    (void)in_sizes; (void)n_in; (void)out_size; (void)ws_size;
    const float* x     = (const float*)d_in[0];
    const float* W_in  = (const float*)d_in[1];
    const float* b_in  = (const float*)d_in[2];
    const float* cw    = (const float*)d_in[3];
    const float* cb    = (const float*)d_in[4];
    const float* W_dt  = (const float*)d_in[5];
    const float* b_dt  = (const float*)d_in[6];
    const float* W_B   = (const float*)d_in[7];
    const float* b_B   = (const float*)d_in[8];
    const float* W_C   = (const float*)d_in[9];
    const float* b_C   = (const float*)d_in[10];
    const float* W_si  = (const float*)d_in[11];
    const float* b_si  = (const float*)d_in[12];
    const float* Dv    = (const float*)d_in[13];
    const float* W_out = (const float*)d_in[14];
    const float* b_out = (const float*)d_in[15];
    float* out = (float*)d_out;

    char* ws = (char*)d_ws;
    u16*   xzb    = (u16*)  (ws);
    u16*   xb     = (u16*)  (ws + 67108864);
    u16*   xact   = (u16*)  (ws + 83886080);
    u16*   hb     = (u16*)  (ws + 117440512);
    float* dtbcT  = (float*)(ws + 150994944);
    float* ybuf   = (float*)(ws + 157286400);
    u16*   ynb    = (u16*)  (ws + 159383552);
    u16*   WinT   = (u16*)  (ws + 160432128);
    u16*   WoutT  = (u16*)  (ws + 168820736);
    u16*   WdtbcT = (u16*)  (ws + 173015040);
    u16*   WsiT   = (u16*)  (ws + 173801472);

    dim3 blk(256);

    // prep: x->bf16, all weight transposes
    convert_bf16<<<dim3((8192L * 1024 / 4 + 255) / 256), blk, 0, stream>>>(x, xb, 8192L * 1024 / 4);
    transpose_big<<<dim3(128, 32, 2), blk, 0, stream>>>(W_in, WinT, W_out, WoutT);
    transpose_small<<<dim3(2, 64, 4), blk, 0, stream>>>(W_dt, W_B, W_C, W_si, WdtbcT, WsiT);

    // xzb = bf16(x @ W_in + b_in)   [8192][4096]
    gemm_mfma<128, 128, 1><<<dim3(32 * 64), blk, 0, stream>>>(
        xb, WinT, b_in, nullptr, nullptr, nullptr, nullptr, xzb, 4096, 1024, 32);
    // xact = silu(causal_conv(xzb[:, :2048]))
    conv_silu<<<dim3(8192L * 2048 / (8 * 256)), blk, 0, stream>>>(xzb, cw, cb, xact);
    // dtbcT[192][8192] = [sigmoid(xact@W_dt+b) | xact@W_B+b | xact@W_C+b]^T
    // BM=32 -> 256 blocks (full chip), WdtbcT stays L2-resident
    gemm_mfma<32, 192, 2><<<dim3(256), blk, 0, stream>>>(
        xact, WdtbcT, b_dt, b_B, b_C, nullptr, nullptr, dtbcT, 192, 2048, 1);
    // y = selective_scan(dt, B, C)   [8192][64]
    scan_kernel<<<dim3(128), blk, 0, stream>>>(dtbcT, ybuf);
    // ynb = bf16(layernorm(y))
    ln_kernel<<<dim3(8192 / 4), blk, 0, stream>>>(ybuf, ynb);
    // hb = (ynb@W_si + b_si + D*xact) * sigmoid(gate)
    gemm_mfma<128, 128, 3><<<dim3(16 * 64), blk, 0, stream>>>(
        ynb, WsiT, b_si, Dv, nullptr, xzb + 2048, xact, hb, 2048, 64, 16);
    // out = hb @ W_out + b_out
    gemm_mfma<128, 128, 0><<<dim3(8 * 64), blk, 0, stream>>>(
        hb, WoutT, b_out, nullptr, nullptr, nullptr, nullptr, out, 1024, 2048, 8);
}